// Round 13
// baseline (678.849 us; speedup 1.0000x reference)
//
#include <hip/hip_runtime.h>
#include <hip/hip_bf16.h>

typedef short short8 __attribute__((ext_vector_type(8)));
typedef float f32x16 __attribute__((ext_vector_type(16)));
typedef float f32x4 __attribute__((ext_vector_type(4)));
typedef float f32x2 __attribute__((ext_vector_type(2)));

// ---------- bf16 helpers ----------
__device__ __forceinline__ unsigned short f2bf(float f) {
  union { float f; unsigned int u; } v; v.f = f;
  unsigned int u = v.u;
  unsigned int r = u + 0x7FFFu + ((u >> 16) & 1u);
  return (unsigned short)(r >> 16);
}
__device__ __forceinline__ float bf2f(unsigned short s) {
  union { unsigned int u; float f; } v; v.u = ((unsigned int)s) << 16;
  return v.f;
}
__device__ __forceinline__ unsigned packbf2(float a, float b) {
  union { __hip_bfloat162 h; unsigned u; } cv;
  cv.h = __hip_bfloat162{__float2bfloat16(a), __float2bfloat16(b)};
  return cv.u;
}

// ---------- erf / GELU (A&S 7.1.25 3-term in s=|t|, |err| <= 2.5e-5) ----------
__device__ __forceinline__ float erfc_core(float u) {   // erfc(u), u>=0 (prep only)
  float e = __expf(-u * u);
  float d = fmaf(0.47047f, u, 1.0f);
  float r = __builtin_amdgcn_rcpf(d);
  float p = fmaf(0.7478556f, r, -0.0958798f);
  p = fmaf(p, r, 0.3480242f);
  p = p * r;
  return p * e;
}
__device__ __forceinline__ f32x2 gelu2(f32x2 t) {
  f32x2 s; s[0] = fabsf(t[0]); s[1] = fabsf(t[1]);
  f32x2 t2 = t * t;
  f32x2 e; e[0] = exp2f(t2[0] * -0.72134752f); e[1] = exp2f(t2[1] * -0.72134752f);
  f32x2 d = s * 0.33270271f + 1.0f;
  f32x2 r; r[0] = __builtin_amdgcn_rcpf(d[0]); r[1] = __builtin_amdgcn_rcpf(d[1]);
  f32x2 p = r * 0.7478556f - 0.0958798f;
  p = p * r + 0.3480242f;
  p = p * r;
  f32x2 wv = p * e;
  f32x2 h = s * 0.5f;
  return t * 0.5f + h - h * wv;
}

// ---------- fused prep: Taylor coeffs (blocks 0..1023) + weight packing ----------
// W2 (32x32x16): frag ((ct*16+ks)*64+lane)*8+j ; k=ks*16+(lane>>5)*8+j ; ch=ct*32+(lane&31)
// W3 (16x16x32, K=256): frag ((ct*8+ks)*64+lane)*8+j ; k=ks*32+((lane>>4)&3)*8+j ; ch=ct*16+(lane&15)
__global__ void k_prep(const float* __restrict__ h, const float* __restrict__ W1,
                       const float* __restrict__ b1,
                       const float* __restrict__ W2, const float* __restrict__ W3,
                       float* __restrict__ p0, float* __restrict__ q1,
                       float* __restrict__ q2,
                       unsigned short* __restrict__ W2H, unsigned short* __restrict__ W2L,
                       unsigned short* __restrict__ A3H, unsigned short* __restrict__ A3L) {
  if (blockIdx.x < 1024) {
    __shared__ float hs[128];
    int g = blockIdx.x, c = threadIdx.x;
    if (c < 128) hs[c] = h[g * 128 + c];
    __syncthreads();
    float acc = b1[c];
#pragma unroll 8
    for (int k = 0; k < 128; k++)
      acc = fmaf(hs[k], W1[(1 + k) * 256 + c], acc);
    float w1c = W1[c];
    float t0 = fmaf(0.5f, w1c, acc);
    float u = fabsf(t0) * 0.7071067811865475f;
    float wq = erfc_core(u);
    float Phi = (t0 >= 0.f) ? fmaf(-0.5f, wq, 1.0f) : 0.5f * wq;
    float phi = 0.3989422804f * __expf(-0.5f * t0 * t0);
    int o = g * 256 + c;
    p0[o] = t0 * Phi;
    q1[o] = w1c * fmaf(t0, phi, Phi);
    q2[o] = (w1c * w1c) * (phi * fmaf(-0.5f * t0, t0, 1.0f));
    return;
  }
  int tid = (blockIdx.x - 1024) * 256 + threadIdx.x;
  if (tid < 65536) {
    int j = tid & 7, lane = (tid >> 3) & 63, ks = (tid >> 9) & 15, ct = tid >> 13;
    int k = ks * 16 + ((lane >> 5) << 3) + j;
    int ch = ct * 32 + (lane & 31);
    float wv = W2[k * 256 + ch];
    unsigned short hi = f2bf(wv);
    W2H[tid] = hi; W2L[tid] = f2bf(wv - bf2f(hi));
  } else if (tid < 65536 + 16384) {
    int t3 = tid - 65536;
    int j = t3 & 7, lane = (t3 >> 3) & 63, ks = (t3 >> 9) & 7, ct = t3 >> 12;
    int k = ks * 32 + ((lane >> 4) & 3) * 8 + j;
    int ch = ct * 16 + (lane & 15);
    float wv = W3[k * 64 + ch];
    unsigned short hi = f2bf(wv);
    A3H[t3] = hi; A3L[t3] = f2bf(wv - bf2f(hi));
  }
}

// zbuf swizzle: byte = row*512 + (colbyte ^ ((row&7)<<4) ^ (((row>>3)&3)<<7))
// ---------- fused main: 64 nodes / 512 threads (8 waves) ----------
// LDS exactly 32 KB and regs <= 64 -> 4 blocks/CU = 32 waves (100% cap).
// No in-loop prefetch (reg frugality); 8 waves/SIMD TLP covers load latency.
__global__ void __launch_bounds__(512, 8)
k_main(const float* __restrict__ x, const int* __restrict__ bidx,
       const float* __restrict__ p0, const float* __restrict__ q1,
       const float* __restrict__ q2,
       const unsigned short* __restrict__ W2H, const unsigned short* __restrict__ W2L,
       const unsigned short* __restrict__ A3H, const unsigned short* __restrict__ A3L,
       const float* __restrict__ b2, const float* __restrict__ b3,
       const float* __restrict__ W4, const float* __restrict__ b4,
       float* __restrict__ out, int N) {
  __shared__ unsigned short zbuf[64 * 256];  // exactly 32 KB, z1 -> z2

  const int t = threadIdx.x;
  const int w = t >> 6, l = t & 63;
  const int l31 = l & 31, lg = l >> 5, l7 = l & 7;
  const int base = blockIdx.x * 64;

  // ---- L1: z1[l][c] = p0 + xm*(q1 + xm*q2); node = lane, wave w owns ch [32w,32w+32) ----
  {
    const int nc = min(base + l, N - 1);
    const float xm = x[nc] - 0.5f;
    const int g = bidx[nc];
    const float* P0 = p0 + g * 256;
    const float* Q1 = q1 + g * 256;
    const float* Q2 = q2 + g * 256;
    const int rswz = ((l & 7) << 4) ^ (((l >> 3) & 3) << 7);
#pragma unroll 2
    for (int it = 0; it < 8; it++) {
      int c = w * 32 + it * 4;
      f32x4 a = *(const f32x4*)(P0 + c);
      f32x4 q = *(const f32x4*)(Q1 + c);
      f32x4 s = *(const f32x4*)(Q2 + c);
      float v0 = fmaf(xm, fmaf(xm, s[0], q[0]), a[0]);
      float v1 = fmaf(xm, fmaf(xm, s[1], q[1]), a[1]);
      float v2 = fmaf(xm, fmaf(xm, s[2], q[2]), a[2]);
      float v3 = fmaf(xm, fmaf(xm, s[3], q[3]), a[3]);
      int byte = l * 512 + ((c * 2) ^ rswz);
      *(uint2*)&zbuf[byte >> 1] = make_uint2(packbf2(v0, v1), packbf2(v2, v3));
    }
  }
  __syncthreads();

  // ---- L2: C[ch 256][node 64]; wave w -> chtile w; direct loads, TLP covers ----
  f32x16 acc[2];
  {
    const int cb = w * 32;
#pragma unroll
    for (int q = 0; q < 4; q++) {
      f32x4 bias = *(const f32x4*)(b2 + cb + 8 * q + 4 * lg);
#pragma unroll
      for (int i = 0; i < 4; i++) { acc[0][4 * q + i] = bias[i]; acc[1][4 * q + i] = bias[i]; }
    }
    const short8* w2h = (const short8*)W2H;
    const short8* w2l = (const short8*)W2L;
    const int fi = w * 1024 + l;
    const int bswz = (l7 << 4) ^ (((l31 >> 3) & 3) << 7);
#pragma unroll 4
    for (int ks = 0; ks < 16; ks++) {
      short8 ah = w2h[fi + ks * 64];
      short8 al = w2l[fi + ks * 64];
      int colx = (ks * 32 + lg * 16) ^ bswz;
      short8 b0 = *(const short8*)&zbuf[(l31 * 512 + colx) >> 1];
      short8 b1v = *(const short8*)&zbuf[((32 + l31) * 512 + colx) >> 1];
      acc[0] = __builtin_amdgcn_mfma_f32_32x32x16_bf16(ah, b0, acc[0], 0, 0, 0);
      acc[1] = __builtin_amdgcn_mfma_f32_32x32x16_bf16(ah, b1v, acc[1], 0, 0, 0);
      acc[0] = __builtin_amdgcn_mfma_f32_32x32x16_bf16(al, b0, acc[0], 0, 0, 0);
      acc[1] = __builtin_amdgcn_mfma_f32_32x32x16_bf16(al, b1v, acc[1], 0, 0, 0);
    }
  }
  __syncthreads();  // all waves done reading z1

  // ---- L2 epilogue: z2 = gelu(acc) -> bf16 LDS (same swizzled layout) ----
  {
    const int cb = w * 32;
#pragma unroll
    for (int q = 0; q < 4; q++) {
      int ch = cb + 8 * q + 4 * lg;
#pragma unroll
      for (int nt2 = 0; nt2 < 2; nt2++) {
        int node = nt2 * 32 + l31;
        f32x2 ga = gelu2(f32x2{acc[nt2][4 * q + 0], acc[nt2][4 * q + 1]});
        f32x2 gb = gelu2(f32x2{acc[nt2][4 * q + 2], acc[nt2][4 * q + 3]});
        int byte = node * 512 + ((ch * 2) ^ ((node & 7) << 4) ^ (((node >> 3) & 3) << 7));
        *(uint2*)&zbuf[byte >> 1] = make_uint2(packbf2(ga[0], ga[1]), packbf2(gb[0], gb[1]));
      }
    }
  }
  __syncthreads();

  // ---- L3 (16x16x32, K=256) + L4 + pool, fully in-register tail ----
  // 16 tiles: tt = 2w+p; ct = tt>>2 (16-ch group), ntl = tt&3 (16-node group).
  {
    const short8* a3h = (const short8*)A3H;
    const short8* a3l = (const short8*)A3L;
    const int lq = (l >> 4) & 3;
    const int l15 = l & 15;
#pragma unroll
    for (int p = 0; p < 2; p++) {
      const int tt = 2 * w + p;
      const int ct = tt >> 2, ntl = tt & 3;
      const int node = ntl * 16 + l15;
      const int bswz = ((node & 7) << 4) ^ (((node >> 3) & 3) << 7);
      f32x4 acc4 = *(const f32x4*)(b3 + ct * 16 + lq * 4);
#pragma unroll 2
      for (int ks = 0; ks < 8; ks++) {
        short8 a3 = a3h[(ct * 8 + ks) * 64 + l];
        short8 a3lo = a3l[(ct * 8 + ks) * 64 + l];
        int colx = (ks * 64 + lq * 16) ^ bswz;
        short8 bfr = *(const short8*)&zbuf[(node * 512 + colx) >> 1];
        acc4 = __builtin_amdgcn_mfma_f32_16x16x32_bf16(a3, bfr, acc4, 0, 0, 0);
        acc4 = __builtin_amdgcn_mfma_f32_16x16x32_bf16(a3lo, bfr, acc4, 0, 0, 0);
      }
      // L4 partial for this ct: e = sum_i gelu(acc4[i]) * W4[ct*16+lq*4+i]
      f32x4 w4v = *(const f32x4*)(W4 + ct * 16 + lq * 4);
      f32x2 ga = gelu2(f32x2{acc4[0], acc4[1]});
      f32x2 gb = gelu2(f32x2{acc4[2], acc4[3]});
      float e = ga[0] * w4v[0] + ga[1] * w4v[1] + gb[0] * w4v[2] + gb[1] * w4v[3];
      e += __shfl_xor(e, 16, 64);
      e += __shfl_xor(e, 32, 64);  // full 16-ch partial, replicated across lq groups

      // per-16-node segmented scan (sorted bidx) then one atomic per run
      const int nn = base + node;
      const bool nv = nn < N;
      int gl = nv ? bidx[min(nn, N - 1)] : -1;
      if (ct == 0) e += b4[0];      // node bias folded into ct==0 partial
      if (!nv) e = 0.f;
#pragma unroll
      for (int d = 1; d < 16; d <<= 1) {
        float eo = __shfl_down(e, d, 64);
        int go = __shfl_down(gl, d, 64);
        if (l15 + d < 16 && go == gl) e += eo;
      }
      int gp = __shfl_up(gl, 1, 64);
      bool head = (l15 == 0) || (gp != gl);
      if (l < 16 && head && nv) atomicAdd(out + gl, e);
    }
  }
}

extern "C" void kernel_launch(void* const* d_in, const int* in_sizes, int n_in,
                              void* d_out, int out_size, void* d_ws, size_t ws_size,
                              hipStream_t stream) {
  const float* x  = (const float*)d_in[0];
  const float* h  = (const float*)d_in[1];
  const int* bidx = (const int*)d_in[2];
  const float* W1 = (const float*)d_in[3];
  const float* b1 = (const float*)d_in[4];
  const float* W2 = (const float*)d_in[5];
  const float* b2 = (const float*)d_in[6];
  const float* W3 = (const float*)d_in[7];
  const float* b3 = (const float*)d_in[8];
  const float* W4 = (const float*)d_in[9];
  const float* b4 = (const float*)d_in[10];
  float* out = (float*)d_out;
  const int N = in_sizes[0];

  char* ws = (char*)d_ws;
  float* p0 = (float*)(ws);
  float* q1 = (float*)(ws + (1 << 20));
  float* q2 = (float*)(ws + (2 << 20));
  unsigned short* W2H = (unsigned short*)(ws + (3 << 20));
  unsigned short* W2L = (unsigned short*)(ws + (3 << 20) + 131072);
  unsigned short* A3H = (unsigned short*)(ws + (3 << 20) + 262144);
  unsigned short* A3L = (unsigned short*)(ws + (3 << 20) + 262144 + 32768);

  hipMemsetAsync(d_out, 0, (size_t)out_size * sizeof(float), stream);
  k_prep<<<1344, 256, 0, stream>>>(h, W1, b1, W2, W3, p0, q1, q2, W2H, W2L, A3H, A3L);
  const int nb = (N + 63) / 64;
  k_main<<<nb, 512, 0, stream>>>(x, bidx, p0, q1, q2, W2H, W2L, A3H, A3L,
                                 b2, b3, W4, b4, out, N);
}

// Round 14
// 386.785 us; speedup vs baseline: 1.7551x; 1.7551x over previous
//
#include <hip/hip_runtime.h>
#include <hip/hip_bf16.h>

typedef short short8 __attribute__((ext_vector_type(8)));
typedef float f32x16 __attribute__((ext_vector_type(16)));
typedef float f32x4 __attribute__((ext_vector_type(4)));
typedef float f32x2 __attribute__((ext_vector_type(2)));

// ---------- bf16 helpers ----------
__device__ __forceinline__ unsigned short f2bf(float f) {
  union { float f; unsigned int u; } v; v.f = f;
  unsigned int u = v.u;
  unsigned int r = u + 0x7FFFu + ((u >> 16) & 1u);
  return (unsigned short)(r >> 16);
}
__device__ __forceinline__ float bf2f(unsigned short s) {
  union { unsigned int u; float f; } v; v.u = ((unsigned int)s) << 16;
  return v.f;
}
__device__ __forceinline__ unsigned packbf2(float a, float b) {
  union { __hip_bfloat162 h; unsigned u; } cv;
  cv.h = __hip_bfloat162{__float2bfloat16(a), __float2bfloat16(b)};
  return cv.u;
}

// ---------- erf / GELU (A&S 7.1.25 3-term, consts folded with sqrt2) ----------
__device__ __forceinline__ float erfc_core(float u) {   // erfc(u), u>=0 (prep only)
  float e = __expf(-u * u);
  float d = fmaf(0.47047f, u, 1.0f);
  float r = __builtin_amdgcn_rcpf(d);
  float p = fmaf(0.7478556f, r, -0.0958798f);
  p = fmaf(p, r, 0.3480242f);
  p = p * r;
  return p * e;
}
__device__ __forceinline__ float gelu1(float t) {
  float s = fabsf(t);
  float e = exp2f(t * t * -0.72134752f);
  float d = fmaf(s, 0.33270271f, 1.0f);
  float r = __builtin_amdgcn_rcpf(d);
  float p = fmaf(0.7478556f, r, -0.0958798f);
  p = fmaf(p, r, 0.3480242f);
  p = p * r;
  float wv = p * e;
  float hh = 0.5f * s;
  return fmaf(0.5f, t, hh) - hh * wv;
}
__device__ __forceinline__ f32x2 gelu2(f32x2 t) {
  f32x2 s; s[0] = fabsf(t[0]); s[1] = fabsf(t[1]);
  f32x2 t2 = t * t;
  f32x2 e; e[0] = exp2f(t2[0] * -0.72134752f); e[1] = exp2f(t2[1] * -0.72134752f);
  f32x2 d = s * 0.33270271f + 1.0f;
  f32x2 r; r[0] = __builtin_amdgcn_rcpf(d[0]); r[1] = __builtin_amdgcn_rcpf(d[1]);
  f32x2 p = r * 0.7478556f - 0.0958798f;
  p = p * r + 0.3480242f;
  p = p * r;
  f32x2 wv = p * e;
  f32x2 h = s * 0.5f;
  return t * 0.5f + h - h * wv;
}

// ---------- fused prep ----------
// blocks 0..1023: Taylor coeffs + per-graph bf16-weight-bias correction corr[g]:
//   corr[g] = E(center; fp32 W2,W3) - E(center; bf16 W2,W3, bf16 z2) — the
//   graph-correlated part of weight rounding error, added back per node.
// blocks 1024+: pack W2 (32x32x16 A-frags) and W3 (16x16x32 A-frags), bf16 single.
__global__ void k_prep(const float* __restrict__ h, const float* __restrict__ W1,
                       const float* __restrict__ b1,
                       const float* __restrict__ W2, const float* __restrict__ W3,
                       const float* __restrict__ W4,
                       const float* __restrict__ b2, const float* __restrict__ b3,
                       float* __restrict__ p0, float* __restrict__ q1,
                       float* __restrict__ q2,
                       unsigned short* __restrict__ W2H, unsigned short* __restrict__ A3H,
                       float* __restrict__ corr) {
  if (blockIdx.x < 1024) {
    __shared__ float hs[128];
    __shared__ float z1c[256], z2f[256], z2b[256];
    int g = blockIdx.x, c = threadIdx.x;
    if (c < 128) hs[c] = h[g * 128 + c];
    __syncthreads();
    float acc = b1[c];
#pragma unroll 8
    for (int k = 0; k < 128; k++)
      acc = fmaf(hs[k], W1[(1 + k) * 256 + c], acc);
    float w1c = W1[c];
    float t0 = fmaf(0.5f, w1c, acc);
    float u = fabsf(t0) * 0.7071067811865475f;
    float wq = erfc_core(u);
    float Phi = (t0 >= 0.f) ? fmaf(-0.5f, wq, 1.0f) : 0.5f * wq;
    float phi = 0.3989422804f * __expf(-0.5f * t0 * t0);
    int o = g * 256 + c;
    float g0 = t0 * Phi;
    p0[o] = g0;
    q1[o] = w1c * fmaf(t0, phi, Phi);
    q2[o] = (w1c * w1c) * (phi * fmaf(-0.5f * t0, t0, 1.0f));
    z1c[c] = g0;
    __syncthreads();
    // L2 at center, fp32 weights vs bf16 weights
    float af = b2[c], ab = b2[c];
#pragma unroll 4
    for (int k = 0; k < 256; k++) {
      float wv = W2[k * 256 + c];
      float z = z1c[k];
      af = fmaf(z, wv, af);
      ab = fmaf(z, bf2f(f2bf(wv)), ab);
    }
    z2f[c] = gelu1(af);
    z2b[c] = bf2f(f2bf(gelu1(ab)));   // kernel stores z2 as bf16
    __syncthreads();
    if (c < 64) {
      float cf = b3[c], cb = b3[c];
#pragma unroll 4
      for (int k = 0; k < 256; k++) {
        float wv = W3[k * 64 + c];
        cf = fmaf(z2f[k], wv, cf);
        cb = fmaf(z2b[k], bf2f(f2bf(wv)), cb);
      }
      float pe = (gelu1(cf) - gelu1(cb)) * W4[c];
#pragma unroll
      for (int d = 1; d < 64; d <<= 1) pe += __shfl_xor(pe, d, 64);
      if (c == 0) corr[g] = pe;
    }
    return;
  }
  int tid = (blockIdx.x - 1024) * 256 + threadIdx.x;
  if (tid < 65536) {
    int j = tid & 7, lane = (tid >> 3) & 63, ks = (tid >> 9) & 15, ct = tid >> 13;
    int k = ks * 16 + ((lane >> 5) << 3) + j;
    int ch = ct * 32 + (lane & 31);
    W2H[tid] = f2bf(W2[k * 256 + ch]);
  } else if (tid < 65536 + 16384) {
    int t3 = tid - 65536;
    int j = t3 & 7, lane = (t3 >> 3) & 63, ks = (t3 >> 9) & 7, ct = t3 >> 12;
    int k = ks * 32 + ((lane >> 4) & 3) * 8 + j;
    int ch = ct * 16 + (lane & 15);
    A3H[t3] = f2bf(W3[k * 64 + ch]);
  }
}

// zbuf swizzle: byte = row*512 + (colbyte ^ ((row&7)<<4) ^ (((row>>3)&3)<<7))
// ---------- fused main: 64 nodes / 512 threads (8 waves); single-bf16 weights ----------
__global__ void __launch_bounds__(512, 6)
k_main(const float* __restrict__ x, const int* __restrict__ bidx,
       const float* __restrict__ p0, const float* __restrict__ q1,
       const float* __restrict__ q2,
       const unsigned short* __restrict__ W2H, const unsigned short* __restrict__ A3H,
       const float* __restrict__ b2, const float* __restrict__ b3,
       const float* __restrict__ W4, const float* __restrict__ b4,
       const float* __restrict__ corr,
       float* __restrict__ out, int N) {
  __shared__ unsigned short zbuf[64 * 256];  // 32 KB, z1 -> z2
  __shared__ float ebuf[64][4];              // per-node chtile partials

  const int t = threadIdx.x;
  const int w = t >> 6, l = t & 63;
  const int l31 = l & 31, lg = l >> 5, l7 = l & 7;
  const int base = blockIdx.x * 64;

  const short8* w2h = (const short8*)W2H;
  const int fi = w * 1024 + l;
  short8 ah = w2h[fi];  // first A-fragment in flight across L1

  const int n = base + l;
  const bool valid = n < N;
  const float xv = valid ? x[n] : 0.0f;
  const int g = valid ? bidx[n] : 0;
  const float xm = xv - 0.5f;
  const int rswz = ((l & 7) << 4) ^ (((l >> 3) & 3) << 7);

  // ---- L1: z1[l][c] = p0 + xm*(q1 + xm*q2); wave w owns channels [32w,32w+32) ----
  {
    const float* P0 = p0 + g * 256;
    const float* Q1 = q1 + g * 256;
    const float* Q2 = q2 + g * 256;
#pragma unroll 2
    for (int it = 0; it < 8; it++) {
      int c = w * 32 + it * 4;
      f32x4 a = *(const f32x4*)(P0 + c);
      f32x4 q = *(const f32x4*)(Q1 + c);
      f32x4 s = *(const f32x4*)(Q2 + c);
      float v0 = fmaf(xm, fmaf(xm, s[0], q[0]), a[0]);
      float v1 = fmaf(xm, fmaf(xm, s[1], q[1]), a[1]);
      float v2 = fmaf(xm, fmaf(xm, s[2], q[2]), a[2]);
      float v3 = fmaf(xm, fmaf(xm, s[3], q[3]), a[3]);
      int byte = l * 512 + ((c * 2) ^ rswz);
      *(uint2*)&zbuf[byte >> 1] = make_uint2(packbf2(v0, v1), packbf2(v2, v3));
    }
  }
  __syncthreads();

  // ---- L2: C[ch 256][node 64]; wave w -> chtile w; 1-deep A prefetch ----
  f32x16 acc[2];
  {
    const int cb = w * 32;
#pragma unroll
    for (int q = 0; q < 4; q++) {
      f32x4 bias = *(const f32x4*)(b2 + cb + 8 * q + 4 * lg);
#pragma unroll
      for (int i = 0; i < 4; i++) { acc[0][4 * q + i] = bias[i]; acc[1][4 * q + i] = bias[i]; }
    }
    const int bswz = (l7 << 4) ^ (((l31 >> 3) & 3) << 7);
#pragma unroll
    for (int ks = 0; ks < 16; ks++) {
      short8 ah_n;
      if (ks < 15) ah_n = w2h[fi + (ks + 1) * 64];
      int colx = (ks * 32 + lg * 16) ^ bswz;
      short8 b0 = *(const short8*)&zbuf[(l31 * 512 + colx) >> 1];
      short8 b1v = *(const short8*)&zbuf[((32 + l31) * 512 + colx) >> 1];
      acc[0] = __builtin_amdgcn_mfma_f32_32x32x16_bf16(ah, b0, acc[0], 0, 0, 0);
      acc[1] = __builtin_amdgcn_mfma_f32_32x32x16_bf16(ah, b1v, acc[1], 0, 0, 0);
      ah = ah_n;
    }
  }
  __syncthreads();  // all waves done reading z1

  // ---- L2 epilogue: z2 = gelu(acc) -> bf16 LDS (same swizzled layout) ----
  {
    const int cb = w * 32;
#pragma unroll
    for (int q = 0; q < 4; q++) {
      int ch = cb + 8 * q + 4 * lg;
#pragma unroll
      for (int nt2 = 0; nt2 < 2; nt2++) {
        int node = nt2 * 32 + l31;
        f32x2 ga = gelu2(f32x2{acc[nt2][4 * q + 0], acc[nt2][4 * q + 1]});
        f32x2 gb = gelu2(f32x2{acc[nt2][4 * q + 2], acc[nt2][4 * q + 3]});
        int byte = node * 512 + ((ch * 2) ^ ((node & 7) << 4) ^ (((node >> 3) & 3) << 7));
        *(uint2*)&zbuf[byte >> 1] = make_uint2(packbf2(ga[0], ga[1]), packbf2(gb[0], gb[1]));
      }
    }
  }
  __syncthreads();

  // ---- L3 (16x16x32, K=256): 16 tiles; wave w -> tiles 2w, 2w+1 ----
  {
    const short8* a3h = (const short8*)A3H;
    const int lq = (l >> 4) & 3;
    const int l15 = l & 15;
#pragma unroll
    for (int p = 0; p < 2; p++) {
      const int tt = 2 * w + p;
      const int ct = tt >> 2, ntl = tt & 3;
      const int node = ntl * 16 + l15;
      const int bswz = ((node & 7) << 4) ^ (((node >> 3) & 3) << 7);
      f32x4 acc4 = *(const f32x4*)(b3 + ct * 16 + lq * 4);
      short8 a3 = a3h[(ct * 8) * 64 + l];
#pragma unroll
      for (int ks = 0; ks < 8; ks++) {
        short8 a3_n;
        if (ks < 7) a3_n = a3h[(ct * 8 + ks + 1) * 64 + l];
        int colx = (ks * 64 + lq * 16) ^ bswz;
        short8 bfr = *(const short8*)&zbuf[(node * 512 + colx) >> 1];
        acc4 = __builtin_amdgcn_mfma_f32_16x16x32_bf16(a3, bfr, acc4, 0, 0, 0);
        a3 = a3_n;
      }
      f32x4 w4v = *(const f32x4*)(W4 + ct * 16 + lq * 4);
      f32x2 ga = gelu2(f32x2{acc4[0], acc4[1]});
      f32x2 gb = gelu2(f32x2{acc4[2], acc4[3]});
      float e = ga[0] * w4v[0] + ga[1] * w4v[1] + gb[0] * w4v[2] + gb[1] * w4v[3];
      e += __shfl_xor(e, 16, 64);
      e += __shfl_xor(e, 32, 64);
      if (l < 16) ebuf[node][ct] = e;
    }
  }
  __syncthreads();

  // ---- pool: wave 0 sums partials + b4 + per-graph correction; scan; atomic ----
  if (w == 0) {
    f32x4 ev = *(const f32x4*)ebuf[l];
    float e = 0.f;
    int gl = -1;
    if (valid) {
      gl = g;
      e = (ev[0] + ev[1]) + (ev[2] + ev[3]) + b4[0] + corr[gl];
    }
#pragma unroll
    for (int d = 1; d < 64; d <<= 1) {
      float eo = __shfl_down(e, d, 64);
      int go = __shfl_down(gl, d, 64);
      if (l + d < 64 && go == gl) e += eo;
    }
    int gp = __shfl_up(gl, 1, 64);
    bool head = (l == 0) || (gp != gl);
    if (head && valid) atomicAdd(out + gl, e);
  }
}

extern "C" void kernel_launch(void* const* d_in, const int* in_sizes, int n_in,
                              void* d_out, int out_size, void* d_ws, size_t ws_size,
                              hipStream_t stream) {
  const float* x  = (const float*)d_in[0];
  const float* h  = (const float*)d_in[1];
  const int* bidx = (const int*)d_in[2];
  const float* W1 = (const float*)d_in[3];
  const float* b1 = (const float*)d_in[4];
  const float* W2 = (const float*)d_in[5];
  const float* b2 = (const float*)d_in[6];
  const float* W3 = (const float*)d_in[7];
  const float* b3 = (const float*)d_in[8];
  const float* W4 = (const float*)d_in[9];
  const float* b4 = (const float*)d_in[10];
  float* out = (float*)d_out;
  const int N = in_sizes[0];

  char* ws = (char*)d_ws;
  float* p0 = (float*)(ws);
  float* q1 = (float*)(ws + (1 << 20));
  float* q2 = (float*)(ws + (2 << 20));
  unsigned short* W2H = (unsigned short*)(ws + (3 << 20));
  unsigned short* A3H = (unsigned short*)(ws + (3 << 20) + 262144);
  float* corr = (float*)(ws + (3 << 20) + 262144 + 32768);

  hipMemsetAsync(d_out, 0, (size_t)out_size * sizeof(float), stream);
  k_prep<<<1344, 256, 0, stream>>>(h, W1, b1, W2, W3, W4, b2, b3,
                                   p0, q1, q2, W2H, A3H, corr);
  const int nb = (N + 63) / 64;
  k_main<<<nb, 512, 0, stream>>>(x, bidx, p0, q1, q2, W2H, A3H,
                                 b2, b3, W4, b4, corr, out, N);
}